// Round 14
// baseline (224.112 us; speedup 1.0000x reference)
//
#include <hip/hip_runtime.h>
#include <math.h>

#define NCLS 19
#define DIM  128
#define CD   (NCLS * DIM)   // 2432 floats
#define WPB  8              // waves per block (512 threads)
#define NBLK 256            // == CU count; 1 block/CU -> all co-resident
#define NTHR 512
#define NWAVES (NBLK * WPB) // 2048 waves grid-wide
#define NRP  40             // pairs held in registers (160 regs; unified
                            // VGPR/AGPR file, cap 256 at launch_bounds(512,2))
#define NLP  8              // pairs held in LDS per wave (8 KB/wave)
#define PPW  64             // pairs per wave in the exact-fit case

typedef float f32x4 __attribute__((ext_vector_type(4)));

// NT for held data only (never re-read). Round-9 proved nt is a no-op for
// L3 allocation on gfx950 (FETCH unchanged), so streamed loads stay cached.
__device__ __forceinline__ float4 ntload4(const float4* p) {
    f32x4 r = __builtin_nontemporal_load((const f32x4*)p);
    return make_float4(r.x, r.y, r.z, r.w);
}

// 32-lane-group sum via DPP on the VALU pipe. Valid in lanes 31 and 63.
template <int CTRL, int RMASK>
__device__ __forceinline__ float dpp_add(float x) {
    int t = __builtin_amdgcn_update_dpp(0, __builtin_bit_cast(int, x),
                                        CTRL, RMASK, 0xf, true);
    return x + __builtin_bit_cast(float, t);
}
__device__ __forceinline__ float reduce32_dpp(float x) {
    x = dpp_add<0x111, 0xf>(x);   // row_shr:1
    x = dpp_add<0x112, 0xf>(x);   // row_shr:2
    x = dpp_add<0x114, 0xf>(x);   // row_shr:4
    x = dpp_add<0x118, 0xf>(x);   // row_shr:8
    x = dpp_add<0x142, 0xa>(x);   // row_bcast15 -> lanes 31/63 hold 32-sums
    return x;
}

// Private-table RMW accumulator (rounds 2/8/10 proven; shared-table
// ds-atomics were 2.4x slower at 2 waves/SIMD -- rounds 5/6).
__device__ __forceinline__ void proc_pair(float* __restrict__ tbl,
                                          int* __restrict__ cnt,
                                          float4 v, int ca, int cb,
                                          int lane, int l31) {
    if (ca == cb) {
        v.x += __shfl_xor(v.x, 32, 64);
        v.y += __shfl_xor(v.y, 32, 64);
        v.z += __shfl_xor(v.z, 32, 64);
        v.w += __shfl_xor(v.w, 32, 64);
        float4* q = (float4*)&tbl[ca * DIM + l31 * 4];
        float4 a = *q;
        a.x += v.x; a.y += v.y; a.z += v.z; a.w += v.w;
        *q = a;
        if (lane == 0) cnt[ca] += 2;
    } else {
        int c = (lane >= 32) ? cb : ca;
        float4* q = (float4*)&tbl[c * DIM + l31 * 4];
        float4 a = *q;
        a.x += v.x; a.y += v.y; a.z += v.z; a.w += v.w;
        *q = a;
        if (lane == 0)  cnt[ca]++;
        if (lane == 32) cnt[cb]++;
    }
}

// ROUND-11 (3rd resubmit; rounds 11/12 infra-failed): round-10 structure
// (depth-4 pipelined loads, timed-window win 230->222) with NRP 28->40:
// held pairs 36/64 -> 48/64, phase-2b re-read 58 MB -> 33.5 MB.
// WRITE_SIZE jump >= 10 MB = spill alarm -> revert to NRP=32.
__global__ __launch_bounds__(NTHR, 2)
void k_fused(const float4* __restrict__ in4, const int* __restrict__ tgt,
             float* __restrict__ gsums, int* __restrict__ gcounts,
             int* __restrict__ bar, float* __restrict__ out,
             int npair, float inv_n) {
    __shared__ __align__(16) float ls[WPB * CD];           // 77824 B
    __shared__ int   lcnt[WPB * NCLS];                     // 608 B
    __shared__ float red[NTHR];                            // 2048 B
    __shared__ __align__(16) float4 holdl[WPB * NLP * 64]; // 65536 B

    const int tid  = threadIdx.x;
    const int w    = tid >> 6;
    const int lane = tid & 63;
    const int l31  = lane & 31;
    float* tbl = &ls[w * CD];
    int*   cnt = &lcnt[w * NCLS];
    const int g = blockIdx.x * WPB + w;      // global wave id, 0..2047

    for (int i = tid; i < WPB * CD; i += NTHR) ls[i] = 0.0f;
    for (int i = tid; i < WPB * NCLS; i += NTHR) lcnt[i] = 0;
    __syncthreads();

    const bool exact = (npair == PPW * NWAVES);
    const int  lstop = exact ? (NRP + NLP) * NWAVES : 0;

    // ---- Phase 1a: register-held pairs, pipelined (load k+4 before proc k)
    float4 hold[NRP];                        // static indices only
    if (exact) {
        int2 a0, a1, a2, a3;
        {   // prologue: batch 0
            const int p0 = 0 * NWAVES + g, p1 = 1 * NWAVES + g;
            const int p2 = 2 * NWAVES + g, p3 = 3 * NWAVES + g;
            hold[0] = ntload4(&in4[(size_t)p0 * 64 + lane]);
            hold[1] = ntload4(&in4[(size_t)p1 * 64 + lane]);
            hold[2] = ntload4(&in4[(size_t)p2 * 64 + lane]);
            hold[3] = ntload4(&in4[(size_t)p3 * 64 + lane]);
            a0 = *(const int2*)&tgt[2 * p0];
            a1 = *(const int2*)&tgt[2 * p1];
            a2 = *(const int2*)&tgt[2 * p2];
            a3 = *(const int2*)&tgt[2 * p3];
        }
        #pragma unroll
        for (int k = 0; k <= NRP - 8; k += 4) {
            const int q0 = (k + 4) * NWAVES + g, q1 = (k + 5) * NWAVES + g;
            const int q2 = (k + 6) * NWAVES + g, q3 = (k + 7) * NWAVES + g;
            hold[k + 4] = ntload4(&in4[(size_t)q0 * 64 + lane]);
            hold[k + 5] = ntload4(&in4[(size_t)q1 * 64 + lane]);
            hold[k + 6] = ntload4(&in4[(size_t)q2 * 64 + lane]);
            hold[k + 7] = ntload4(&in4[(size_t)q3 * 64 + lane]);
            int2 b0 = *(const int2*)&tgt[2 * q0];
            int2 b1 = *(const int2*)&tgt[2 * q1];
            int2 b2 = *(const int2*)&tgt[2 * q2];
            int2 b3 = *(const int2*)&tgt[2 * q3];
            proc_pair(tbl, cnt, hold[k + 0], a0.x, a0.y, lane, l31);
            proc_pair(tbl, cnt, hold[k + 1], a1.x, a1.y, lane, l31);
            proc_pair(tbl, cnt, hold[k + 2], a2.x, a2.y, lane, l31);
            proc_pair(tbl, cnt, hold[k + 3], a3.x, a3.y, lane, l31);
            a0 = b0; a1 = b1; a2 = b2; a3 = b3;
        }
        proc_pair(tbl, cnt, hold[NRP - 4], a0.x, a0.y, lane, l31);
        proc_pair(tbl, cnt, hold[NRP - 3], a1.x, a1.y, lane, l31);
        proc_pair(tbl, cnt, hold[NRP - 2], a2.x, a2.y, lane, l31);
        proc_pair(tbl, cnt, hold[NRP - 1], a3.x, a3.y, lane, l31);
        // ANCHOR: asm-produce every held value so the compiler cannot
        // rematerialize the loads in phase 2 (round-1 failure mode).
        #pragma unroll
        for (int k = 0; k < NRP; k++) {
            asm volatile("" : "+v"(hold[k].x), "+v"(hold[k].y),
                              "+v"(hold[k].z), "+v"(hold[k].w));
        }

        // ---- Phase 1c: LDS-held pairs (2 batches, load 1 before proc 0) ----
        float4* hbase = &holdl[(size_t)(w * NLP) * 64 + lane];
        {
            const int p0 = (NRP + 0) * NWAVES + g, p1 = (NRP + 1) * NWAVES + g;
            const int p2 = (NRP + 2) * NWAVES + g, p3 = (NRP + 3) * NWAVES + g;
            float4 c0 = ntload4(&in4[(size_t)p0 * 64 + lane]);
            float4 c1 = ntload4(&in4[(size_t)p1 * 64 + lane]);
            float4 c2 = ntload4(&in4[(size_t)p2 * 64 + lane]);
            float4 c3 = ntload4(&in4[(size_t)p3 * 64 + lane]);
            int2 d0 = *(const int2*)&tgt[2 * p0];
            int2 d1 = *(const int2*)&tgt[2 * p1];
            int2 d2 = *(const int2*)&tgt[2 * p2];
            int2 d3 = *(const int2*)&tgt[2 * p3];
            const int q0 = (NRP + 4) * NWAVES + g, q1 = (NRP + 5) * NWAVES + g;
            const int q2 = (NRP + 6) * NWAVES + g, q3 = (NRP + 7) * NWAVES + g;
            float4 e0 = ntload4(&in4[(size_t)q0 * 64 + lane]);
            float4 e1 = ntload4(&in4[(size_t)q1 * 64 + lane]);
            float4 e2 = ntload4(&in4[(size_t)q2 * 64 + lane]);
            float4 e3 = ntload4(&in4[(size_t)q3 * 64 + lane]);
            int2 f0 = *(const int2*)&tgt[2 * q0];
            int2 f1 = *(const int2*)&tgt[2 * q1];
            int2 f2 = *(const int2*)&tgt[2 * q2];
            int2 f3 = *(const int2*)&tgt[2 * q3];
            hbase[0 * 64] = c0; hbase[1 * 64] = c1;
            hbase[2 * 64] = c2; hbase[3 * 64] = c3;
            proc_pair(tbl, cnt, c0, d0.x, d0.y, lane, l31);
            proc_pair(tbl, cnt, c1, d1.x, d1.y, lane, l31);
            proc_pair(tbl, cnt, c2, d2.x, d2.y, lane, l31);
            proc_pair(tbl, cnt, c3, d3.x, d3.y, lane, l31);
            hbase[4 * 64] = e0; hbase[5 * 64] = e1;
            hbase[6 * 64] = e2; hbase[7 * 64] = e3;
            proc_pair(tbl, cnt, e0, f0.x, f0.y, lane, l31);
            proc_pair(tbl, cnt, e1, f1.x, f1.y, lane, l31);
            proc_pair(tbl, cnt, e2, f2.x, f2.y, lane, l31);
            proc_pair(tbl, cnt, e3, f3.x, f3.y, lane, l31);
        }
    }

    // ---- Phase 1b: streamed pairs, depth-4 pipelined (cached loads) ----
    int p = lstop + g;
    if (p + 3 * NWAVES < npair) {
        float4 v0 = in4[(size_t)(p             ) * 64 + lane];
        float4 v1 = in4[(size_t)(p +     NWAVES) * 64 + lane];
        float4 v2 = in4[(size_t)(p + 2 * NWAVES) * 64 + lane];
        float4 v3 = in4[(size_t)(p + 3 * NWAVES) * 64 + lane];
        int2 ab0 = *(const int2*)&tgt[2 * p];
        int2 ab1 = *(const int2*)&tgt[2 * (p + NWAVES)];
        int2 ab2 = *(const int2*)&tgt[2 * (p + 2 * NWAVES)];
        int2 ab3 = *(const int2*)&tgt[2 * (p + 3 * NWAVES)];
        while (p + 7 * NWAVES < npair) {
            const int pn = p + 4 * NWAVES;
            float4 n0 = in4[(size_t)(pn             ) * 64 + lane];
            float4 n1 = in4[(size_t)(pn +     NWAVES) * 64 + lane];
            float4 n2 = in4[(size_t)(pn + 2 * NWAVES) * 64 + lane];
            float4 n3 = in4[(size_t)(pn + 3 * NWAVES) * 64 + lane];
            int2 m0 = *(const int2*)&tgt[2 * pn];
            int2 m1 = *(const int2*)&tgt[2 * (pn + NWAVES)];
            int2 m2 = *(const int2*)&tgt[2 * (pn + 2 * NWAVES)];
            int2 m3 = *(const int2*)&tgt[2 * (pn + 3 * NWAVES)];
            proc_pair(tbl, cnt, v0, ab0.x, ab0.y, lane, l31);
            proc_pair(tbl, cnt, v1, ab1.x, ab1.y, lane, l31);
            proc_pair(tbl, cnt, v2, ab2.x, ab2.y, lane, l31);
            proc_pair(tbl, cnt, v3, ab3.x, ab3.y, lane, l31);
            v0 = n0; v1 = n1; v2 = n2; v3 = n3;
            ab0 = m0; ab1 = m1; ab2 = m2; ab3 = m3;
            p = pn;
        }
        proc_pair(tbl, cnt, v0, ab0.x, ab0.y, lane, l31);
        proc_pair(tbl, cnt, v1, ab1.x, ab1.y, lane, l31);
        proc_pair(tbl, cnt, v2, ab2.x, ab2.y, lane, l31);
        proc_pair(tbl, cnt, v3, ab3.x, ab3.y, lane, l31);
        p += 4 * NWAVES;
    }
    for (; p < npair; p += NWAVES) {
        float4 v = in4[(size_t)p * 64 + lane];
        int2 ab = *(const int2*)&tgt[2 * p];
        proc_pair(tbl, cnt, v, ab.x, ab.y, lane, l31);
    }
    __syncthreads();

    // ---- Cross-wave reduce -> device-scope atomics ----
    for (int i = tid; i < CD; i += NTHR) {
        float s = 0.0f;
        #pragma unroll
        for (int ww = 0; ww < WPB; ww++) s += ls[ww * CD + i];
        unsafeAtomicAdd(&gsums[i], s);
    }
    if (tid < NCLS) {
        int s = 0;
        #pragma unroll
        for (int ww = 0; ww < WPB; ww++) s += lcnt[ww * NCLS + tid];
        atomicAdd(&gcounts[tid], s);
    }

    // ---- Software grid barrier (device-scope; 1 block/CU co-residency) ----
    __syncthreads();
    if (tid == 0) {
        __hip_atomic_fetch_add(bar, 1, __ATOMIC_ACQ_REL,
                               __HIP_MEMORY_SCOPE_AGENT);
        while (__hip_atomic_load(bar, __ATOMIC_ACQUIRE,
                                 __HIP_MEMORY_SCOPE_AGENT) < NBLK) {
            __builtin_amdgcn_s_sleep(8);
        }
    }
    __syncthreads();

    // ---- Centers to LDS, ALIASING the dead private tables ----
    float* lcent = ls;
    for (int i = tid; i < CD; i += NTHR) {
        float s = __hip_atomic_load(&gsums[i], __ATOMIC_RELAXED,
                                    __HIP_MEMORY_SCOPE_AGENT);
        int   c = __hip_atomic_load(&gcounts[i >> 7], __ATOMIC_RELAXED,
                                    __HIP_MEMORY_SCOPE_AGENT);
        lcent[i] = s / (float)c;
    }
    __syncthreads();

    float acc = 0.0f;

    if (exact) {
        // ---- Phase 2a: register-held pairs (zero global input traffic) ----
        #pragma unroll
        for (int k = 0; k < NRP; k++) {
            const int pk = k * NWAVES + g;
            const int2 cc = *(const int2*)&tgt[2 * pk];
            const int c = (lane >= 32) ? cc.y : cc.x;
            const float4 e = *(const float4*)&lcent[c * DIM + l31 * 4];
            const float4 v = hold[k];
            float dx = v.x - e.x, dy = v.y - e.y;
            float dz = v.z - e.z, dw = v.w - e.w;
            float d = dx * dx + dy * dy + dz * dz + dw * dw;
            d = reduce32_dpp(d);
            if (l31 == 31) acc += sqrtf(d);   // lanes 31 & 63
        }
        // ---- Phase 2c: LDS-held pairs ----
        const float4* hbase = &holdl[(size_t)(w * NLP) * 64 + lane];
        #pragma unroll
        for (int k = 0; k < NLP; k++) {
            const int pk = (NRP + k) * NWAVES + g;
            const int2 cc = *(const int2*)&tgt[2 * pk];
            const int c = (lane >= 32) ? cc.y : cc.x;
            float4 v = hbase[k * 64];
            const float4 e = *(const float4*)&lcent[c * DIM + l31 * 4];
            float dx = v.x - e.x, dy = v.y - e.y;
            float dz = v.z - e.z, dw = v.w - e.w;
            float d = dx * dx + dy * dy + dz * dz + dw * dw;
            d = reduce32_dpp(d);
            if (l31 == 31) acc += sqrtf(d);
        }
    }

    // ---- Phase 2b: streamed re-read, depth-4 pipelined (L3-resident) ----
    int q = lstop + g;
    if (q + 3 * NWAVES < npair) {
        float4 v0 = in4[(size_t)(q             ) * 64 + lane];
        float4 v1 = in4[(size_t)(q +     NWAVES) * 64 + lane];
        float4 v2 = in4[(size_t)(q + 2 * NWAVES) * 64 + lane];
        float4 v3 = in4[(size_t)(q + 3 * NWAVES) * 64 + lane];
        int2 ab0 = *(const int2*)&tgt[2 * q];
        int2 ab1 = *(const int2*)&tgt[2 * (q + NWAVES)];
        int2 ab2 = *(const int2*)&tgt[2 * (q + 2 * NWAVES)];
        int2 ab3 = *(const int2*)&tgt[2 * (q + 3 * NWAVES)];
        while (q + 7 * NWAVES < npair) {
            const int qn = q + 4 * NWAVES;
            float4 n0 = in4[(size_t)(qn             ) * 64 + lane];
            float4 n1 = in4[(size_t)(qn +     NWAVES) * 64 + lane];
            float4 n2 = in4[(size_t)(qn + 2 * NWAVES) * 64 + lane];
            float4 n3 = in4[(size_t)(qn + 3 * NWAVES) * 64 + lane];
            int2 m0 = *(const int2*)&tgt[2 * qn];
            int2 m1 = *(const int2*)&tgt[2 * (qn + NWAVES)];
            int2 m2 = *(const int2*)&tgt[2 * (qn + 2 * NWAVES)];
            int2 m3 = *(const int2*)&tgt[2 * (qn + 3 * NWAVES)];
            #pragma unroll
            for (int j = 0; j < 4; j++) {
                float4 v = (j == 0) ? v0 : (j == 1) ? v1 : (j == 2) ? v2 : v3;
                int2  cc = (j == 0) ? ab0 : (j == 1) ? ab1 : (j == 2) ? ab2 : ab3;
                int c = (lane >= 32) ? cc.y : cc.x;
                const float4 e = *(const float4*)&lcent[c * DIM + l31 * 4];
                float dx = v.x - e.x, dy = v.y - e.y;
                float dz = v.z - e.z, dw = v.w - e.w;
                float d = dx * dx + dy * dy + dz * dz + dw * dw;
                d = reduce32_dpp(d);
                if (l31 == 31) acc += sqrtf(d);
            }
            v0 = n0; v1 = n1; v2 = n2; v3 = n3;
            ab0 = m0; ab1 = m1; ab2 = m2; ab3 = m3;
            q = qn;
        }
        #pragma unroll
        for (int j = 0; j < 4; j++) {
            float4 v = (j == 0) ? v0 : (j == 1) ? v1 : (j == 2) ? v2 : v3;
            int2  cc = (j == 0) ? ab0 : (j == 1) ? ab1 : (j == 2) ? ab2 : ab3;
            int c = (lane >= 32) ? cc.y : cc.x;
            const float4 e = *(const float4*)&lcent[c * DIM + l31 * 4];
            float dx = v.x - e.x, dy = v.y - e.y;
            float dz = v.z - e.z, dw = v.w - e.w;
            float d = dx * dx + dy * dy + dz * dz + dw * dw;
            d = reduce32_dpp(d);
            if (l31 == 31) acc += sqrtf(d);
        }
        q += 4 * NWAVES;
    }
    for (; q < npair; q += NWAVES) {
        float4 v = in4[(size_t)q * 64 + lane];
        int2 c2 = *(const int2*)&tgt[2 * q];
        int c = (lane >= 32) ? c2.y : c2.x;
        const float4 e = *(const float4*)&lcent[c * DIM + l31 * 4];
        float dx = v.x - e.x, dy = v.y - e.y, dz = v.z - e.z, dw = v.w - e.w;
        float d = dx * dx + dy * dy + dz * dz + dw * dw;
        d = reduce32_dpp(d);
        if (l31 == 31) acc += sqrtf(d);
    }

    red[tid] = acc;
    __syncthreads();
    for (int s = NTHR / 2; s > 0; s >>= 1) {
        if (tid < s) red[tid] += red[tid + s];
        __syncthreads();
    }
    if (tid == 0) unsafeAtomicAdd(out, red[0] * inv_n);
}

extern "C" void kernel_launch(void* const* d_in, const int* in_sizes, int n_in,
                              void* d_out, int out_size, void* d_ws, size_t ws_size,
                              hipStream_t stream) {
    const float* in  = (const float*)d_in[0];
    const int*   tgt = (const int*)d_in[1];
    const int n = in_sizes[0] / DIM;       // 262144

    float* gsums   = (float*)d_ws;             // [19][128]
    int*   gcounts = (int*)(gsums + CD);       // [19]
    int*   bar     = gcounts + NCLS;           // grid-barrier counter
    float* out     = (float*)d_out;

    (void)hipMemsetAsync(d_ws, 0, (CD + NCLS + 1) * sizeof(float), stream);
    (void)hipMemsetAsync(d_out, 0, sizeof(float), stream);

    const float4* in4 = (const float4*)in;
    k_fused<<<NBLK, NTHR, 0, stream>>>(in4, tgt, gsums, gcounts, bar,
                                       out, n / 2, 1.0f / (float)n);
}

// Round 15
// 222.261 us; speedup vs baseline: 1.0083x; 1.0083x over previous
//
#include <hip/hip_runtime.h>
#include <math.h>

#define NCLS 19
#define DIM  128
#define CD   (NCLS * DIM)   // 2432 floats
#define WPB  8              // waves per block (512 threads)
#define NBLK 256            // == CU count; 1 block/CU -> all co-resident
#define NTHR 512
#define NWAVES (NBLK * WPB) // 2048 waves grid-wide
#define NRP  28             // pairs held in registers. ROUND-15: revert to
                            // round-10's measured best (222.3us); NRP=40
                            // (round 14) was 224.1 -- re-read bytes are off
                            // the timed critical path, so extra hold only
                            // adds register pressure.
#define NLP  8              // pairs held in LDS per wave (8 KB/wave)
#define PPW  64             // pairs per wave in the exact-fit case

typedef float f32x4 __attribute__((ext_vector_type(4)));

// NT for held data only (never re-read). Round-9 proved nt is a no-op for
// L3 allocation on gfx950 (FETCH unchanged), so streamed loads stay cached.
__device__ __forceinline__ float4 ntload4(const float4* p) {
    f32x4 r = __builtin_nontemporal_load((const f32x4*)p);
    return make_float4(r.x, r.y, r.z, r.w);
}

// 32-lane-group sum via DPP on the VALU pipe. Valid in lanes 31 and 63.
template <int CTRL, int RMASK>
__device__ __forceinline__ float dpp_add(float x) {
    int t = __builtin_amdgcn_update_dpp(0, __builtin_bit_cast(int, x),
                                        CTRL, RMASK, 0xf, true);
    return x + __builtin_bit_cast(float, t);
}
__device__ __forceinline__ float reduce32_dpp(float x) {
    x = dpp_add<0x111, 0xf>(x);   // row_shr:1
    x = dpp_add<0x112, 0xf>(x);   // row_shr:2
    x = dpp_add<0x114, 0xf>(x);   // row_shr:4
    x = dpp_add<0x118, 0xf>(x);   // row_shr:8
    x = dpp_add<0x142, 0xa>(x);   // row_bcast15 -> lanes 31/63 hold 32-sums
    return x;
}

// Private-table RMW accumulator (rounds 2/8/10 proven; shared-table
// ds-atomics were 2.4x slower at 2 waves/SIMD -- rounds 5/6).
__device__ __forceinline__ void proc_pair(float* __restrict__ tbl,
                                          int* __restrict__ cnt,
                                          float4 v, int ca, int cb,
                                          int lane, int l31) {
    if (ca == cb) {
        v.x += __shfl_xor(v.x, 32, 64);
        v.y += __shfl_xor(v.y, 32, 64);
        v.z += __shfl_xor(v.z, 32, 64);
        v.w += __shfl_xor(v.w, 32, 64);
        float4* q = (float4*)&tbl[ca * DIM + l31 * 4];
        float4 a = *q;
        a.x += v.x; a.y += v.y; a.z += v.z; a.w += v.w;
        *q = a;
        if (lane == 0) cnt[ca] += 2;
    } else {
        int c = (lane >= 32) ? cb : ca;
        float4* q = (float4*)&tbl[c * DIM + l31 * 4];
        float4 a = *q;
        a.x += v.x; a.y += v.y; a.z += v.z; a.w += v.w;
        *q = a;
        if (lane == 0)  cnt[ca]++;
        if (lane == 32) cnt[cb]++;
    }
}

// ROUND-15 = exact round-10 kernel (measured best, 222.3us total).
// Depth-4 software-pipelined loads keep ~8KB/wave in flight across the
// serial LDS RMW chains (the timed-window lever: -8us vs non-pipelined).
__global__ __launch_bounds__(NTHR, 2)
void k_fused(const float4* __restrict__ in4, const int* __restrict__ tgt,
             float* __restrict__ gsums, int* __restrict__ gcounts,
             int* __restrict__ bar, float* __restrict__ out,
             int npair, float inv_n) {
    __shared__ __align__(16) float ls[WPB * CD];           // 77824 B
    __shared__ int   lcnt[WPB * NCLS];                     // 608 B
    __shared__ float red[NTHR];                            // 2048 B
    __shared__ __align__(16) float4 holdl[WPB * NLP * 64]; // 65536 B

    const int tid  = threadIdx.x;
    const int w    = tid >> 6;
    const int lane = tid & 63;
    const int l31  = lane & 31;
    float* tbl = &ls[w * CD];
    int*   cnt = &lcnt[w * NCLS];
    const int g = blockIdx.x * WPB + w;      // global wave id, 0..2047

    for (int i = tid; i < WPB * CD; i += NTHR) ls[i] = 0.0f;
    for (int i = tid; i < WPB * NCLS; i += NTHR) lcnt[i] = 0;
    __syncthreads();

    const bool exact = (npair == PPW * NWAVES);
    const int  lstop = exact ? (NRP + NLP) * NWAVES : 0;

    // ---- Phase 1a: register-held pairs, pipelined (load k+4 before proc k)
    float4 hold[NRP];                        // static indices only
    if (exact) {
        int2 a0, a1, a2, a3;
        {   // prologue: batch 0
            const int p0 = 0 * NWAVES + g, p1 = 1 * NWAVES + g;
            const int p2 = 2 * NWAVES + g, p3 = 3 * NWAVES + g;
            hold[0] = ntload4(&in4[(size_t)p0 * 64 + lane]);
            hold[1] = ntload4(&in4[(size_t)p1 * 64 + lane]);
            hold[2] = ntload4(&in4[(size_t)p2 * 64 + lane]);
            hold[3] = ntload4(&in4[(size_t)p3 * 64 + lane]);
            a0 = *(const int2*)&tgt[2 * p0];
            a1 = *(const int2*)&tgt[2 * p1];
            a2 = *(const int2*)&tgt[2 * p2];
            a3 = *(const int2*)&tgt[2 * p3];
        }
        #pragma unroll
        for (int k = 0; k <= NRP - 8; k += 4) {
            const int q0 = (k + 4) * NWAVES + g, q1 = (k + 5) * NWAVES + g;
            const int q2 = (k + 6) * NWAVES + g, q3 = (k + 7) * NWAVES + g;
            hold[k + 4] = ntload4(&in4[(size_t)q0 * 64 + lane]);
            hold[k + 5] = ntload4(&in4[(size_t)q1 * 64 + lane]);
            hold[k + 6] = ntload4(&in4[(size_t)q2 * 64 + lane]);
            hold[k + 7] = ntload4(&in4[(size_t)q3 * 64 + lane]);
            int2 b0 = *(const int2*)&tgt[2 * q0];
            int2 b1 = *(const int2*)&tgt[2 * q1];
            int2 b2 = *(const int2*)&tgt[2 * q2];
            int2 b3 = *(const int2*)&tgt[2 * q3];
            proc_pair(tbl, cnt, hold[k + 0], a0.x, a0.y, lane, l31);
            proc_pair(tbl, cnt, hold[k + 1], a1.x, a1.y, lane, l31);
            proc_pair(tbl, cnt, hold[k + 2], a2.x, a2.y, lane, l31);
            proc_pair(tbl, cnt, hold[k + 3], a3.x, a3.y, lane, l31);
            a0 = b0; a1 = b1; a2 = b2; a3 = b3;
        }
        proc_pair(tbl, cnt, hold[NRP - 4], a0.x, a0.y, lane, l31);
        proc_pair(tbl, cnt, hold[NRP - 3], a1.x, a1.y, lane, l31);
        proc_pair(tbl, cnt, hold[NRP - 2], a2.x, a2.y, lane, l31);
        proc_pair(tbl, cnt, hold[NRP - 1], a3.x, a3.y, lane, l31);
        // ANCHOR: asm-produce every held value so the compiler cannot
        // rematerialize the loads in phase 2 (round-1 failure mode).
        #pragma unroll
        for (int k = 0; k < NRP; k++) {
            asm volatile("" : "+v"(hold[k].x), "+v"(hold[k].y),
                              "+v"(hold[k].z), "+v"(hold[k].w));
        }

        // ---- Phase 1c: LDS-held pairs (2 batches, load 1 before proc 0) ----
        float4* hbase = &holdl[(size_t)(w * NLP) * 64 + lane];
        {
            const int p0 = (NRP + 0) * NWAVES + g, p1 = (NRP + 1) * NWAVES + g;
            const int p2 = (NRP + 2) * NWAVES + g, p3 = (NRP + 3) * NWAVES + g;
            float4 c0 = ntload4(&in4[(size_t)p0 * 64 + lane]);
            float4 c1 = ntload4(&in4[(size_t)p1 * 64 + lane]);
            float4 c2 = ntload4(&in4[(size_t)p2 * 64 + lane]);
            float4 c3 = ntload4(&in4[(size_t)p3 * 64 + lane]);
            int2 d0 = *(const int2*)&tgt[2 * p0];
            int2 d1 = *(const int2*)&tgt[2 * p1];
            int2 d2 = *(const int2*)&tgt[2 * p2];
            int2 d3 = *(const int2*)&tgt[2 * p3];
            const int q0 = (NRP + 4) * NWAVES + g, q1 = (NRP + 5) * NWAVES + g;
            const int q2 = (NRP + 6) * NWAVES + g, q3 = (NRP + 7) * NWAVES + g;
            float4 e0 = ntload4(&in4[(size_t)q0 * 64 + lane]);
            float4 e1 = ntload4(&in4[(size_t)q1 * 64 + lane]);
            float4 e2 = ntload4(&in4[(size_t)q2 * 64 + lane]);
            float4 e3 = ntload4(&in4[(size_t)q3 * 64 + lane]);
            int2 f0 = *(const int2*)&tgt[2 * q0];
            int2 f1 = *(const int2*)&tgt[2 * q1];
            int2 f2 = *(const int2*)&tgt[2 * q2];
            int2 f3 = *(const int2*)&tgt[2 * q3];
            hbase[0 * 64] = c0; hbase[1 * 64] = c1;
            hbase[2 * 64] = c2; hbase[3 * 64] = c3;
            proc_pair(tbl, cnt, c0, d0.x, d0.y, lane, l31);
            proc_pair(tbl, cnt, c1, d1.x, d1.y, lane, l31);
            proc_pair(tbl, cnt, c2, d2.x, d2.y, lane, l31);
            proc_pair(tbl, cnt, c3, d3.x, d3.y, lane, l31);
            hbase[4 * 64] = e0; hbase[5 * 64] = e1;
            hbase[6 * 64] = e2; hbase[7 * 64] = e3;
            proc_pair(tbl, cnt, e0, f0.x, f0.y, lane, l31);
            proc_pair(tbl, cnt, e1, f1.x, f1.y, lane, l31);
            proc_pair(tbl, cnt, e2, f2.x, f2.y, lane, l31);
            proc_pair(tbl, cnt, e3, f3.x, f3.y, lane, l31);
        }
    }

    // ---- Phase 1b: streamed pairs, depth-4 pipelined (cached loads) ----
    int p = lstop + g;
    if (p + 3 * NWAVES < npair) {
        float4 v0 = in4[(size_t)(p             ) * 64 + lane];
        float4 v1 = in4[(size_t)(p +     NWAVES) * 64 + lane];
        float4 v2 = in4[(size_t)(p + 2 * NWAVES) * 64 + lane];
        float4 v3 = in4[(size_t)(p + 3 * NWAVES) * 64 + lane];
        int2 ab0 = *(const int2*)&tgt[2 * p];
        int2 ab1 = *(const int2*)&tgt[2 * (p + NWAVES)];
        int2 ab2 = *(const int2*)&tgt[2 * (p + 2 * NWAVES)];
        int2 ab3 = *(const int2*)&tgt[2 * (p + 3 * NWAVES)];
        while (p + 7 * NWAVES < npair) {
            const int pn = p + 4 * NWAVES;
            float4 n0 = in4[(size_t)(pn             ) * 64 + lane];
            float4 n1 = in4[(size_t)(pn +     NWAVES) * 64 + lane];
            float4 n2 = in4[(size_t)(pn + 2 * NWAVES) * 64 + lane];
            float4 n3 = in4[(size_t)(pn + 3 * NWAVES) * 64 + lane];
            int2 m0 = *(const int2*)&tgt[2 * pn];
            int2 m1 = *(const int2*)&tgt[2 * (pn + NWAVES)];
            int2 m2 = *(const int2*)&tgt[2 * (pn + 2 * NWAVES)];
            int2 m3 = *(const int2*)&tgt[2 * (pn + 3 * NWAVES)];
            proc_pair(tbl, cnt, v0, ab0.x, ab0.y, lane, l31);
            proc_pair(tbl, cnt, v1, ab1.x, ab1.y, lane, l31);
            proc_pair(tbl, cnt, v2, ab2.x, ab2.y, lane, l31);
            proc_pair(tbl, cnt, v3, ab3.x, ab3.y, lane, l31);
            v0 = n0; v1 = n1; v2 = n2; v3 = n3;
            ab0 = m0; ab1 = m1; ab2 = m2; ab3 = m3;
            p = pn;
        }
        proc_pair(tbl, cnt, v0, ab0.x, ab0.y, lane, l31);
        proc_pair(tbl, cnt, v1, ab1.x, ab1.y, lane, l31);
        proc_pair(tbl, cnt, v2, ab2.x, ab2.y, lane, l31);
        proc_pair(tbl, cnt, v3, ab3.x, ab3.y, lane, l31);
        p += 4 * NWAVES;
    }
    for (; p < npair; p += NWAVES) {
        float4 v = in4[(size_t)p * 64 + lane];
        int2 ab = *(const int2*)&tgt[2 * p];
        proc_pair(tbl, cnt, v, ab.x, ab.y, lane, l31);
    }
    __syncthreads();

    // ---- Cross-wave reduce -> device-scope atomics ----
    for (int i = tid; i < CD; i += NTHR) {
        float s = 0.0f;
        #pragma unroll
        for (int ww = 0; ww < WPB; ww++) s += ls[ww * CD + i];
        unsafeAtomicAdd(&gsums[i], s);
    }
    if (tid < NCLS) {
        int s = 0;
        #pragma unroll
        for (int ww = 0; ww < WPB; ww++) s += lcnt[ww * NCLS + tid];
        atomicAdd(&gcounts[tid], s);
    }

    // ---- Software grid barrier (device-scope; 1 block/CU co-residency) ----
    __syncthreads();
    if (tid == 0) {
        __hip_atomic_fetch_add(bar, 1, __ATOMIC_ACQ_REL,
                               __HIP_MEMORY_SCOPE_AGENT);
        while (__hip_atomic_load(bar, __ATOMIC_ACQUIRE,
                                 __HIP_MEMORY_SCOPE_AGENT) < NBLK) {
            __builtin_amdgcn_s_sleep(8);
        }
    }
    __syncthreads();

    // ---- Centers to LDS, ALIASING the dead private tables ----
    float* lcent = ls;
    for (int i = tid; i < CD; i += NTHR) {
        float s = __hip_atomic_load(&gsums[i], __ATOMIC_RELAXED,
                                    __HIP_MEMORY_SCOPE_AGENT);
        int   c = __hip_atomic_load(&gcounts[i >> 7], __ATOMIC_RELAXED,
                                    __HIP_MEMORY_SCOPE_AGENT);
        lcent[i] = s / (float)c;
    }
    __syncthreads();

    float acc = 0.0f;

    if (exact) {
        // ---- Phase 2a: register-held pairs (zero global input traffic) ----
        #pragma unroll
        for (int k = 0; k < NRP; k++) {
            const int pk = k * NWAVES + g;
            const int2 cc = *(const int2*)&tgt[2 * pk];
            const int c = (lane >= 32) ? cc.y : cc.x;
            const float4 e = *(const float4*)&lcent[c * DIM + l31 * 4];
            const float4 v = hold[k];
            float dx = v.x - e.x, dy = v.y - e.y;
            float dz = v.z - e.z, dw = v.w - e.w;
            float d = dx * dx + dy * dy + dz * dz + dw * dw;
            d = reduce32_dpp(d);
            if (l31 == 31) acc += sqrtf(d);   // lanes 31 & 63
        }
        // ---- Phase 2c: LDS-held pairs ----
        const float4* hbase = &holdl[(size_t)(w * NLP) * 64 + lane];
        #pragma unroll
        for (int k = 0; k < NLP; k++) {
            const int pk = (NRP + k) * NWAVES + g;
            const int2 cc = *(const int2*)&tgt[2 * pk];
            const int c = (lane >= 32) ? cc.y : cc.x;
            float4 v = hbase[k * 64];
            const float4 e = *(const float4*)&lcent[c * DIM + l31 * 4];
            float dx = v.x - e.x, dy = v.y - e.y;
            float dz = v.z - e.z, dw = v.w - e.w;
            float d = dx * dx + dy * dy + dz * dz + dw * dw;
            d = reduce32_dpp(d);
            if (l31 == 31) acc += sqrtf(d);
        }
    }

    // ---- Phase 2b: streamed re-read, depth-4 pipelined (L3-resident) ----
    int q = lstop + g;
    if (q + 3 * NWAVES < npair) {
        float4 v0 = in4[(size_t)(q             ) * 64 + lane];
        float4 v1 = in4[(size_t)(q +     NWAVES) * 64 + lane];
        float4 v2 = in4[(size_t)(q + 2 * NWAVES) * 64 + lane];
        float4 v3 = in4[(size_t)(q + 3 * NWAVES) * 64 + lane];
        int2 ab0 = *(const int2*)&tgt[2 * q];
        int2 ab1 = *(const int2*)&tgt[2 * (q + NWAVES)];
        int2 ab2 = *(const int2*)&tgt[2 * (q + 2 * NWAVES)];
        int2 ab3 = *(const int2*)&tgt[2 * (q + 3 * NWAVES)];
        while (q + 7 * NWAVES < npair) {
            const int qn = q + 4 * NWAVES;
            float4 n0 = in4[(size_t)(qn             ) * 64 + lane];
            float4 n1 = in4[(size_t)(qn +     NWAVES) * 64 + lane];
            float4 n2 = in4[(size_t)(qn + 2 * NWAVES) * 64 + lane];
            float4 n3 = in4[(size_t)(qn + 3 * NWAVES) * 64 + lane];
            int2 m0 = *(const int2*)&tgt[2 * qn];
            int2 m1 = *(const int2*)&tgt[2 * (qn + NWAVES)];
            int2 m2 = *(const int2*)&tgt[2 * (qn + 2 * NWAVES)];
            int2 m3 = *(const int2*)&tgt[2 * (qn + 3 * NWAVES)];
            #pragma unroll
            for (int j = 0; j < 4; j++) {
                float4 v = (j == 0) ? v0 : (j == 1) ? v1 : (j == 2) ? v2 : v3;
                int2  cc = (j == 0) ? ab0 : (j == 1) ? ab1 : (j == 2) ? ab2 : ab3;
                int c = (lane >= 32) ? cc.y : cc.x;
                const float4 e = *(const float4*)&lcent[c * DIM + l31 * 4];
                float dx = v.x - e.x, dy = v.y - e.y;
                float dz = v.z - e.z, dw = v.w - e.w;
                float d = dx * dx + dy * dy + dz * dz + dw * dw;
                d = reduce32_dpp(d);
                if (l31 == 31) acc += sqrtf(d);
            }
            v0 = n0; v1 = n1; v2 = n2; v3 = n3;
            ab0 = m0; ab1 = m1; ab2 = m2; ab3 = m3;
            q = qn;
        }
        #pragma unroll
        for (int j = 0; j < 4; j++) {
            float4 v = (j == 0) ? v0 : (j == 1) ? v1 : (j == 2) ? v2 : v3;
            int2  cc = (j == 0) ? ab0 : (j == 1) ? ab1 : (j == 2) ? ab2 : ab3;
            int c = (lane >= 32) ? cc.y : cc.x;
            const float4 e = *(const float4*)&lcent[c * DIM + l31 * 4];
            float dx = v.x - e.x, dy = v.y - e.y;
            float dz = v.z - e.z, dw = v.w - e.w;
            float d = dx * dx + dy * dy + dz * dz + dw * dw;
            d = reduce32_dpp(d);
            if (l31 == 31) acc += sqrtf(d);
        }
        q += 4 * NWAVES;
    }
    for (; q < npair; q += NWAVES) {
        float4 v = in4[(size_t)q * 64 + lane];
        int2 c2 = *(const int2*)&tgt[2 * q];
        int c = (lane >= 32) ? c2.y : c2.x;
        const float4 e = *(const float4*)&lcent[c * DIM + l31 * 4];
        float dx = v.x - e.x, dy = v.y - e.y, dz = v.z - e.z, dw = v.w - e.w;
        float d = dx * dx + dy * dy + dz * dz + dw * dw;
        d = reduce32_dpp(d);
        if (l31 == 31) acc += sqrtf(d);
    }

    red[tid] = acc;
    __syncthreads();
    for (int s = NTHR / 2; s > 0; s >>= 1) {
        if (tid < s) red[tid] += red[tid + s];
        __syncthreads();
    }
    if (tid == 0) unsafeAtomicAdd(out, red[0] * inv_n);
}

extern "C" void kernel_launch(void* const* d_in, const int* in_sizes, int n_in,
                              void* d_out, int out_size, void* d_ws, size_t ws_size,
                              hipStream_t stream) {
    const float* in  = (const float*)d_in[0];
    const int*   tgt = (const int*)d_in[1];
    const int n = in_sizes[0] / DIM;       // 262144

    float* gsums   = (float*)d_ws;             // [19][128]
    int*   gcounts = (int*)(gsums + CD);       // [19]
    int*   bar     = gcounts + NCLS;           // grid-barrier counter
    float* out     = (float*)d_out;

    (void)hipMemsetAsync(d_ws, 0, (CD + NCLS + 1) * sizeof(float), stream);
    (void)hipMemsetAsync(d_out, 0, sizeof(float), stream);

    const float4* in4 = (const float4*)in;
    k_fused<<<NBLK, NTHR, 0, stream>>>(in4, tgt, gsums, gcounts, bar,
                                       out, n / 2, 1.0f / (float)n);
}